// Round 1
// baseline (1441.683 us; speedup 1.0000x reference)
//
#include <hip/hip_runtime.h>
#include <stdint.h>

#define NN 16384   // nodes
#define NC 16      // colors
#define NB 64      // graphs

struct Mults { unsigned long long m[17]; };

// ---------------- kernels ----------------

// Build per-64-column color bitmasks matching the ballot bit layout of k_hist:
// idx = (chunk*4 + k)*16 + c ; bit l of table[idx] = (x[chunk*256 + l*4 + k] == c)
__global__ __launch_bounds__(256) void k_table(const int* __restrict__ x,
                                               unsigned long long* __restrict__ table) {
  int idx = blockIdx.x * 256 + threadIdx.x;        // 4096 entries
  int c = idx & 15, k = (idx >> 4) & 3, chunk = idx >> 6;
  unsigned long long m = 0ull;
  for (int l = 0; l < 64; ++l) {
    int col = chunk * 256 + l * 4 + k;
    if (x[col] == c) m |= (1ull << l);
  }
  table[idx] = m;
}

// One wave per row: neighbor color histogram via ballots + mask popcounts.
__global__ __launch_bounds__(256) void k_hist(const float* __restrict__ adj,
                                              const unsigned long long* __restrict__ table,
                                              int* __restrict__ nbr_hist) {
  __shared__ unsigned long long tbl[4096];
  for (int i = threadIdx.x; i < 4096; i += 256) tbl[i] = table[i];
  __syncthreads();
  int wave = threadIdx.x >> 6;
  int lane = threadIdx.x & 63;
  int row  = blockIdx.x * 4 + wave;
  const uint4* rowp = (const uint4*)(adj + (size_t)row * NN);
  int c = lane & 15, k = lane >> 4;
  const unsigned long long* tk = &tbl[k * 16 + c];
  int cnt = 0;
  for (int chunk = 0; chunk < 64; ++chunk) {
    uint4 v = rowp[chunk * 64 + lane];             // 1 KiB per wave, coalesced
    unsigned long long b0 = __ballot(v.x != 0u);
    unsigned long long b1 = __ballot(v.y != 0u);
    unsigned long long b2 = __ballot(v.z != 0u);
    unsigned long long b3 = __ballot(v.w != 0u);
    unsigned long long m = (k & 2) ? ((k & 1) ? b3 : b2) : ((k & 1) ? b1 : b0);
    cnt += __popcll(m & tk[chunk * 64]);
  }
  cnt += __shfl_xor(cnt, 16, 64);
  cnt += __shfl_xor(cnt, 32, 64);
  if (lane < 16) nbr_hist[row * 16 + lane] = cnt;
}

// rowsum==0 nodes become "suspects" needing a column check (expected: none).
__global__ __launch_bounds__(256) void k_rowsum(const int* __restrict__ nbr_hist,
                                                int* __restrict__ colany,
                                                int* __restrict__ suspects,
                                                int* __restrict__ scount) {
  int i = blockIdx.x * 256 + threadIdx.x;
  int rs = 0;
  for (int c = 0; c < 16; ++c) rs += nbr_hist[i * 16 + c];
  colany[i] = 1;   // default: not isolated (only consulted when rs==0)
  if (rs == 0) { int s = atomicAdd(scount, 1); suspects[s] = i; }
}

// Check columns of suspect nodes only (exits immediately if no suspects).
__global__ __launch_bounds__(256) void k_colcheck(const float* __restrict__ adj,
                                                  const int* __restrict__ suspects,
                                                  const int* __restrict__ scount,
                                                  int* __restrict__ colany) {
  __shared__ int red[256];
  int nsus = *scount;
  for (int u = blockIdx.x; u < nsus; u += gridDim.x) {
    int col = suspects[u];
    int any = 0;
    for (int r = threadIdx.x; r < NN; r += 256)
      any |= (adj[(size_t)r * NN + col] != 0.0f);
    red[threadIdx.x] = any;
    __syncthreads();
    for (int s = 128; s > 0; s >>= 1) {
      if (threadIdx.x < s) red[threadIdx.x] |= red[threadIdx.x + s];
      __syncthreads();
    }
    if (threadIdx.x == 0) colany[col] = red[0];
    __syncthreads();
  }
}

// 64-bit wraparound polynomial hash; iso nodes forced to INT64_MIN.
__global__ __launch_bounds__(256) void k_hash(const int* __restrict__ x,
                                              const int* __restrict__ nbr_hist,
                                              const int* __restrict__ colany,
                                              Mults M,
                                              unsigned long long* __restrict__ h,
                                              int* __restrict__ iso) {
  int i = blockIdx.x * 256 + threadIdx.x;
  unsigned long long acc = (unsigned long long)(long long)x[i] * M.m[0];
  int rs = 0;
  for (int c = 0; c < 16; ++c) {
    int v = nbr_hist[i * 16 + c];
    rs += v;
    acc += (unsigned long long)(long long)v * M.m[c + 1];
  }
  int is_iso = (rs == 0) && (colany[i] == 0);
  iso[i] = is_iso;
  h[i] = is_iso ? 0x8000000000000000ull : acc;
}

// firsts[i] = min{ j : h[j]==h[i] }, brute force over j-chunks of 2048 in LDS.
#define JC 2048
__global__ __launch_bounds__(256) void k_firsts_part(const unsigned long long* __restrict__ h,
                                                     int* __restrict__ part) {
  __shared__ unsigned long long hs[JC];
  int chunk = blockIdx.y;
  int jbase = chunk * JC;
  for (int t = threadIdx.x; t < JC; t += 256) hs[t] = h[jbase + t];
  __syncthreads();
  int i = blockIdx.x * 256 + threadIdx.x;
  unsigned long long hi = h[i];
  int best = 0x7fffffff;
  for (int jj = 0; jj < JC; ++jj) {
    if (hs[jj] == hi) best = min(best, jbase + jj);
  }
  part[chunk * NN + i] = best;
}

__global__ __launch_bounds__(256) void k_firsts_merge(const int* __restrict__ part,
                                                      int* __restrict__ firsts) {
  int i = blockIdx.x * 256 + threadIdx.x;
  int best = 0x7fffffff;
  for (int ch = 0; ch < NN / JC; ++ch) best = min(best, part[ch * NN + i]);
  firsts[i] = best;
}

// rank = inclusive prefix sum of is_first over node index (single block).
__global__ __launch_bounds__(1024) void k_scan(const int* __restrict__ iso,
                                               const int* __restrict__ firsts,
                                               int* __restrict__ rank) {
  __shared__ int sums[1024];
  int t = threadIdx.x;
  int base = t * 16;
  int loc[16];
  int s = 0;
  for (int u = 0; u < 16; ++u) {
    int i = base + u;
    int isf = (!iso[i]) && (firsts[i] == i);
    s += isf;
    loc[u] = s;                       // inclusive within segment
  }
  sums[t] = s;
  __syncthreads();
  for (int off = 1; off < 1024; off <<= 1) {
    int add = (t >= off) ? sums[t - off] : 0;
    __syncthreads();
    sums[t] += add;
    __syncthreads();
  }
  int excl = sums[t] - s;             // exclusive prefix of this thread's segment
  for (int u = 0; u < 16; ++u) rank[base + u] = excl + loc[u];
}

__global__ __launch_bounds__(256) void k_colors(const int* __restrict__ iso,
                                                const int* __restrict__ firsts,
                                                const int* __restrict__ rank,
                                                int* __restrict__ colors,
                                                float* __restrict__ out_colors) {
  int i = blockIdx.x * 256 + threadIdx.x;
  int c = iso[i] ? 0 : rank[firsts[i]];
  colors[i] = c;
  out_colors[i] = (float)c;
}

__global__ __launch_bounds__(256) void k_count(const int* __restrict__ colors,
                                               const int* __restrict__ batch,
                                               int* __restrict__ cnt) {
  int i = blockIdx.x * 256 + threadIdx.x;
  int c = colors[i];
  if (c > 0) atomicAdd(&cnt[(size_t)batch[i] * NN + (c - 1)], 1);
}

__global__ __launch_bounds__(256) void k_norm(const int* __restrict__ cnt,
                                              float* __restrict__ out) {
  __shared__ float red[256];
  int b = blockIdx.x;
  float ss = 0.0f;
  for (int j = threadIdx.x; j < NN; j += 256) {
    float v = (float)cnt[(size_t)b * NN + j];
    ss += v * v;
  }
  red[threadIdx.x] = ss;
  __syncthreads();
  for (int s = 128; s > 0; s >>= 1) {
    if (threadIdx.x < s) red[threadIdx.x] += red[threadIdx.x + s];
    __syncthreads();
  }
  float nrm = sqrtf(red[0]);
  for (int j = threadIdx.x; j < NN; j += 256)
    out[(size_t)b * NN + j] = (float)cnt[(size_t)b * NN + j] / nrm;
}

// ---------------- host: numpy RandomState(42) MULTS replication ----------------

struct MTState { uint32_t mt[624]; int idx; };

static void mt_seed(MTState& s, uint32_t seed) {
  s.mt[0] = seed;
  for (int i = 1; i < 624; ++i)
    s.mt[i] = 1812433253u * (s.mt[i - 1] ^ (s.mt[i - 1] >> 30)) + (uint32_t)i;
  s.idx = 624;
}

static uint32_t mt_next(MTState& s) {
  if (s.idx >= 624) {
    for (int i = 0; i < 624; ++i) {
      uint32_t y = (s.mt[i] & 0x80000000u) | (s.mt[(i + 1) % 624] & 0x7fffffffu);
      uint32_t nx = s.mt[(i + 397) % 624] ^ (y >> 1);
      if (y & 1u) nx ^= 2567483615u;
      s.mt[i] = nx;
    }
    s.idx = 0;
  }
  uint32_t y = s.mt[s.idx++];
  y ^= y >> 11;
  y ^= (y << 7) & 2636928640u;
  y ^= (y << 15) & 4022730752u;
  y ^= y >> 18;
  return y;
}

static uint64_t mt_next64(MTState& s) {
  uint64_t hi = mt_next(s);
  uint64_t lo = mt_next(s);
  return (hi << 32) | lo;
}

// ---------------- launch ----------------

extern "C" void kernel_launch(void* const* d_in, const int* in_sizes, int n_in,
                              void* d_out, int out_size, void* d_ws, size_t ws_size,
                              hipStream_t stream) {
  const int*   x     = (const int*)d_in[0];
  const float* adj   = (const float*)d_in[1];
  const int*   batch = (const int*)d_in[2];
  float* out_hist   = (float*)d_out;                    // [NB, NN]
  float* out_colors = out_hist + (size_t)NB * NN;       // [NN]

  char* ws = (char*)d_ws;
  // region0 (reused): table/nbr_hist/h/part live first, then cnt overlays them
  unsigned long long* table = (unsigned long long*)(ws + 0);         // 32 KiB
  int*                nhist = (int*)(ws + 32768);                    // 1 MiB
  unsigned long long* h     = (unsigned long long*)(ws + 1081344);   // 128 KiB
  int*                part  = (int*)(ws + 1212416);                  // 512 KiB
  int*                cnt   = (int*)(ws + 0);                        // 4 MiB (overlays the above)
  // region1 (long-lived), starts at 4 MiB
  int* colany   = (int*)(ws + 4194304);
  int* suspects = (int*)(ws + 4259840);
  int* scount   = (int*)(ws + 4325376);
  int* iso      = (int*)(ws + 4325632);
  int* firsts   = (int*)(ws + 4391168);
  int* rank     = (int*)(ws + 4456704);
  int* colors   = (int*)(ws + 4522240);

  // Replicate np.random.RandomState(42).randint(1, 2**62, 17) << 1 | 1
  // (legacy masked rejection: mask = 2^62-1, accept <= 2^62-2, high word first)
  Mults M;
  {
    MTState st;
    mt_seed(st, 42u);
    const uint64_t mask62 = (1ull << 62) - 1ull;
    const uint64_t rng    = (1ull << 62) - 2ull;
    for (int i = 0; i < 17; ++i) {
      uint64_t v;
      do { v = mt_next64(st) & mask62; } while (v > rng);
      M.m[i] = ((1ull + v) << 1) | 1ull;
    }
  }

  hipMemsetAsync(scount, 0, 4, stream);
  k_table<<<16, 256, 0, stream>>>(x, table);
  k_hist<<<NN / 4, 256, 0, stream>>>(adj, table, nhist);
  k_rowsum<<<NN / 256, 256, 0, stream>>>(nhist, colany, suspects, scount);
  k_colcheck<<<64, 256, 0, stream>>>(adj, suspects, scount, colany);
  k_hash<<<NN / 256, 256, 0, stream>>>(x, nhist, colany, M, h, iso);
  dim3 ge(NN / 256, NN / JC);
  k_firsts_part<<<ge, 256, 0, stream>>>(h, part);
  k_firsts_merge<<<NN / 256, 256, 0, stream>>>(part, firsts);
  k_scan<<<1, 1024, 0, stream>>>(iso, firsts, rank);
  k_colors<<<NN / 256, 256, 0, stream>>>(iso, firsts, rank, colors, out_colors);
  hipMemsetAsync(cnt, 0, (size_t)NB * NN * 4, stream);
  k_count<<<NN / 256, 256, 0, stream>>>(colors, batch, cnt);
  k_norm<<<NB, 256, 0, stream>>>(cnt, out_hist);
}